// Round 1
// baseline (533.112 us; speedup 1.0000x reference)
//
#include <hip/hip_runtime.h>

// dx[n,l,o] = weight[o,l] — broadcast transpose of weight (OUT x L) into (N, L, OUT).
// N=128, L=1024, OUT=1024. Output 512 MiB f32: pure HBM-write-bound.
//
// Restructure vs previous version: full-OUT row tiles. Each block owns TL=8
// consecutive l-rows across the ENTIRE o extent; each wave owns 2 consecutive
// l-rows and emits them as an 8 KiB fully-sequential store run per n-slice
// (previous version emitted 256 B chunks at 4 KiB stride — DRAM-page hostile,
// measured ~2.9 TB/s effective vs 6.3 TB/s fill ceiling).

typedef float f32x4 __attribute__((ext_vector_type(4)));

constexpr int TL = 8;        // l-rows per block (full OUT width per row)
constexpr int S = 1028;      // LDS row stride in floats; 1028 % 32 == 4 -> max 2-way bank alias (free)
constexpr int NCHUNK = 16;   // n-slices written per block

__global__ __launch_bounds__(256) void bcast_rows_kernel(
    const float* __restrict__ w, float* __restrict__ out,
    int L, int OUT, long long slice_elems /* L*OUT */) {
  __shared__ float lds[TL * S];  // 8 x 1028 x 4B = 32.9 KiB -> 4 blocks/CU

  const int t = threadIdx.x;
  const int l_base = blockIdx.x * TL;
  const int n_base = blockIdx.y * NCHUNK;

  // ---- Load weight slice w[o][l_base .. l_base+7] for all o, transpose into
  //      lds[l][o]. Thread t: o = (t>>1) + 128*i, c = t&1 covers l = 4c..4c+3.
  //      Reads are 32 B per o-row (tiny total: 32 KiB/block, LLC-resident).
  {
    const int c = t & 1;
    const int o0 = t >> 1;
#pragma unroll
    for (int i = 0; i < 8; ++i) {
      const int o = o0 + 128 * i;
      const f32x4 v = *reinterpret_cast<const f32x4*>(
          w + (size_t)o * L + l_base + 4 * c);
      // bank = ((4c+j)*1028 + o) % 32 = (16c + 4j + o) % 32 -> 2-way max (free)
      lds[(4 * c + 0) * S + o] = v.x;
      lds[(4 * c + 1) * S + o] = v.y;
      lds[(4 * c + 2) * S + o] = v.z;
      lds[(4 * c + 3) * S + o] = v.w;
    }
  }
  __syncthreads();

  // ---- Wave wv owns l = 2*wv and 2*wv+1. Lane covers o = lane*4 + 256*i.
  //      Pull both full rows (8 f32x4 = 32 VGPRs) into registers once.
  const int wv = t >> 6;
  const int lane = t & 63;
  f32x4 vals[2][4];
#pragma unroll
  for (int li = 0; li < 2; ++li) {
    const int l = 2 * wv + li;
#pragma unroll
    for (int i = 0; i < 4; ++i) {
      vals[li][i] = *reinterpret_cast<const f32x4*>(
          &lds[(size_t)l * S + lane * 4 + 256 * i]);
    }
  }

  // ---- Broadcast-write to NCHUNK n-slices. Per wave per n: 8 consecutive
  //      dwordx4 stores covering an 8 KiB sequential run (offsets fold into
  //      the 13-bit signed immediate). Block union per n = 32 KiB sequential.
  const float* cbase = out;  // silence unused warnings pattern
  (void)cbase;
  float* base = out + (size_t)(l_base + 2 * wv) * OUT + (size_t)lane * 4;
  for (int ni = 0; ni < NCHUNK; ++ni) {
    float* outn = base + (size_t)(n_base + ni) * slice_elems;
#pragma unroll
    for (int li = 0; li < 2; ++li) {
#pragma unroll
      for (int i = 0; i < 4; ++i) {
        __builtin_nontemporal_store(
            vals[li][i],
            reinterpret_cast<f32x4*>(outn + (size_t)li * OUT + i * 256));
      }
    }
  }
}

extern "C" void kernel_launch(void* const* d_in, const int* in_sizes, int n_in,
                              void* d_out, int out_size, void* d_ws, size_t ws_size,
                              hipStream_t stream) {
  const float* w = (const float*)d_in[1];  // weight: (OUT, L)
  float* out = (float*)d_out;              // (N, L, OUT)

  const int L = 1024;
  const int N = in_sizes[0] / L;            // 128
  const int OUT = in_sizes[1] / L;          // 1024
  const long long slice = (long long)L * OUT;

  dim3 grid(L / TL, N / NCHUNK);  // (128, 8) = 1024 blocks, 4 blocks/CU
  dim3 block(256);
  bcast_rows_kernel<<<grid, block, 0, stream>>>(w, out, L, OUT, slice);
}